// Round 1
// baseline (1910.930 us; speedup 1.0000x reference)
//
#include <hip/hip_runtime.h>

#define DD 64
#define ROW 256   // output row stride in floats: D*(L+1)

// ---- copy entity_embed -> d_out slice 0 -------------------------------------
__global__ void k_copy_embed(const float* __restrict__ ent, float* __restrict__ out, int n_rows) {
    int idx = blockIdx.x * blockDim.x + threadIdx.x;   // over n_rows*16 float4s
    int total = n_rows * 16;
    if (idx >= total) return;
    int n = idx >> 4, q = idx & 15;
    const float4* src = (const float4*)(ent + (long)n * DD);
    float4* dst = (float4*)(out + (long)n * ROW);
    dst[q] = src[q];
}

// ---- copy slice l -> slice l+1 (init for agg accumulation: acc = h) ---------
__global__ void k_dup_slice(float* __restrict__ out, int n_rows, int l) {
    int idx = blockIdx.x * blockDim.x + threadIdx.x;
    int total = n_rows * 16;
    if (idx >= total) return;
    int n = idx >> 4, q = idx & 15;
    const float4* src = (const float4*)(out + (long)n * ROW + l * DD);
    float4* dst = (float4*)(out + (long)n * ROW + (l + 1) * DD);
    dst[q] = src[q];
}

// ---- per-edge score: sexp[e] = exp(e_t . tanh(e_h+e_r)); ssum[head] += ------
// wave per edge; lane d handles dim d. hbase = d_out + l*64 (row stride ROW).
__global__ __launch_bounds__(256) void k_score(
        const int* __restrict__ heads, const int* __restrict__ rels,
        const int* __restrict__ tails,
        const float* __restrict__ hbase, const float* __restrict__ relemb,
        float* __restrict__ sexp, float* __restrict__ ssum, int nE) {
    int e = blockIdx.x * 4 + (threadIdx.x >> 6);
    if (e >= nE) return;
    int lane = threadIdx.x & 63;
    int hd = heads[e], tl = tails[e], rl = rels[e];
    float hh = hbase[(long)hd * ROW + lane];
    float tt = hbase[(long)tl * ROW + lane];
    float rr = relemb[rl * DD + lane];
    float v = tt * tanhf(hh + rr);
    #pragma unroll
    for (int off = 32; off; off >>= 1) v += __shfl_xor(v, off);
    if (lane == 0) {
        float se = expf(v);
        sexp[e] = se;
        atomicAdd(ssum + hd, se);
    }
}

// ---- per-edge aggregate: acc[head] += (sexp/(ssum+1e-10)) * e_t -------------
__global__ __launch_bounds__(256) void k_agg(
        const int* __restrict__ heads, const int* __restrict__ tails,
        const float* __restrict__ hbase, float* __restrict__ accbase,
        const float* __restrict__ sexp, const float* __restrict__ ssum, int nE) {
    int e = blockIdx.x * 4 + (threadIdx.x >> 6);
    if (e >= nE) return;
    int lane = threadIdx.x & 63;
    int hd = heads[e], tl = tails[e];
    float w = sexp[e] / (ssum[hd] + 1e-10f);
    float val = w * hbase[(long)tl * ROW + lane];
    atomicAdd(accbase + (long)hd * ROW + lane, val);
}

// ---- in-place row transform: x -> leaky_relu(x @ W^T) -----------------------
// wave per row (4 rows/block). W [64,64] row-major; Wt in LDS transposed so
// lane-j reads Wt[k*64+j] (2-way bank alias = free on gfx950).
__global__ __launch_bounds__(256) void k_linear(
        float* __restrict__ accbase, const float* __restrict__ W, int n_rows) {
    __shared__ float Wt[DD * DD];
    __shared__ float xs[4][DD];
    for (int idx = threadIdx.x; idx < DD * DD; idx += 256) {
        int k = idx >> 6, j = idx & 63;
        Wt[idx] = W[j * DD + k];          // Wt[k][j] = W[j][k]
    }
    int row = blockIdx.x * 4 + (threadIdx.x >> 6);
    int lane = threadIdx.x & 63;
    int w = threadIdx.x >> 6;
    bool valid = row < n_rows;
    float x = 0.f;
    if (valid) x = accbase[(long)row * ROW + lane];
    xs[w][lane] = x;
    __syncthreads();
    float acc = 0.f;
    #pragma unroll
    for (int k = 0; k < DD; ++k)
        acc += xs[w][k] * Wt[k * DD + lane];
    float y = acc >= 0.f ? acc : 0.2f * acc;
    if (valid) accbase[(long)row * ROW + lane] = y;
}

extern "C" void kernel_launch(void* const* d_in, const int* in_sizes, int n_in,
                              void* d_out, int out_size, void* d_ws, size_t ws_size,
                              hipStream_t stream) {
    const int*   heads = (const int*)d_in[0];
    const int*   rels  = (const int*)d_in[1];
    const int*   tails = (const int*)d_in[2];
    const float* ent   = (const float*)d_in[3];
    const float* rel   = (const float*)d_in[4];
    const float* Ws    = (const float*)d_in[5];
    float* out = (float*)d_out;

    const int nE = in_sizes[0];
    const int N  = in_sizes[3] / DD;
    const int L  = in_sizes[5] / (DD * DD);
    const int NREL = in_sizes[4] / (L * DD);

    float* sexp = (float*)d_ws;        // [E]
    float* ssum = sexp + nE;           // [N]

    dim3 blk(256);
    int copy_blocks = (N * 16 + 255) / 256;
    int edge_blocks = (nE + 3) / 4;
    int row_blocks  = (N + 3) / 4;

    k_copy_embed<<<copy_blocks, blk, 0, stream>>>(ent, out, N);

    for (int l = 0; l < L; ++l) {
        k_dup_slice<<<copy_blocks, blk, 0, stream>>>(out, N, l);
        hipMemsetAsync(ssum, 0, (size_t)N * sizeof(float), stream);
        k_score<<<edge_blocks, blk, 0, stream>>>(
            heads, rels, tails, out + l * DD, rel + (long)l * NREL * DD,
            sexp, ssum, nE);
        k_agg<<<edge_blocks, blk, 0, stream>>>(
            heads, tails, out + l * DD, out + (l + 1) * DD, sexp, ssum, nE);
        k_linear<<<row_blocks, blk, 0, stream>>>(
            out + (l + 1) * DD, Ws + (long)l * DD * DD, N);
    }
}

// Round 3
// 964.598 us; speedup vs baseline: 1.9811x; 1.9811x over previous
//
#include <hip/hip_runtime.h>

#define DD 64
#define ROW 256        // output row stride in floats: D*(L+1)
#define CHUNK 1024     // scan chunk

// ---- copy entity_embed -> d_out slice 0 -------------------------------------
__global__ void k_copy_embed(const float* __restrict__ ent, float* __restrict__ out, int n_rows) {
    int idx = blockIdx.x * blockDim.x + threadIdx.x;   // over n_rows*16 float4s
    int total = n_rows * 16;
    if (idx >= total) return;
    int n = idx >> 4, q = idx & 15;
    const float4* src = (const float4*)(ent + (long)n * DD);
    float4* dst = (float4*)(out + (long)n * ROW);
    dst[q] = src[q];
}

// ---- CSR build: count edges per head ---------------------------------------
__global__ void k_count(const int* __restrict__ heads, int* __restrict__ counts, int nE) {
    int e = blockIdx.x * 256 + threadIdx.x;
    if (e >= nE) return;
    atomicAdd(counts + heads[e], 1);
}

// ---- scan step 1: per-chunk exclusive scan + chunk totals -------------------
__global__ __launch_bounds__(256) void k_scan_chunk(
        const int* __restrict__ counts, int* __restrict__ offs,
        int* __restrict__ partials, int n) {
    __shared__ int lds[256];
    int base = blockIdx.x * CHUNK;
    int t = threadIdx.x;
    int c[4]; int sum = 0;
    #pragma unroll
    for (int j = 0; j < 4; ++j) {
        int i = base + t * 4 + j;
        c[j] = (i < n) ? counts[i] : 0;
        sum += c[j];
    }
    lds[t] = sum; __syncthreads();
    for (int d = 1; d < 256; d <<= 1) {
        int v = (t >= d) ? lds[t - d] : 0;
        __syncthreads();
        lds[t] += v;
        __syncthreads();
    }
    int excl = lds[t] - sum;
    if (t == 255) partials[blockIdx.x] = lds[255];
    int run = excl;
    #pragma unroll
    for (int j = 0; j < 4; ++j) {
        int i = base + t * 4 + j;
        if (i < n) offs[i] = run;
        run += c[j];
    }
}

// ---- scan step 2: exclusive scan of chunk totals (nb <= 128) ----------------
__global__ __launch_bounds__(128) void k_scan_part(int* __restrict__ partials, int nb) {
    __shared__ int lds[128];
    int t = threadIdx.x;
    int v = (t < nb) ? partials[t] : 0;
    lds[t] = v; __syncthreads();
    for (int d = 1; d < 128; d <<= 1) {
        int u = (t >= d) ? lds[t - d] : 0;
        __syncthreads();
        lds[t] += u;
        __syncthreads();
    }
    if (t < nb) partials[t] = lds[t] - v;
}

// ---- scan step 3: add chunk offsets, finalize offs[n] = nE ------------------
__global__ void k_scan_add(int* __restrict__ offs, const int* __restrict__ partials,
                           int n, int nE) {
    int i = blockIdx.x * 256 + threadIdx.x;
    if (i < n)       offs[i] += partials[i >> 10];
    else if (i == n) offs[n] = nE;
}

// ---- scatter edges into CSR order; pack tail | (rel<<20) --------------------
__global__ void k_scatter(const int* __restrict__ heads, const int* __restrict__ rels,
                          const int* __restrict__ tails, int* __restrict__ running,
                          int* __restrict__ packed, int nE) {
    int e = blockIdx.x * 256 + threadIdx.x;
    if (e >= nE) return;
    int h = heads[e];
    int pos = atomicAdd(running + h, 1);
    packed[pos] = tails[e] | (rels[e] << 20);
}

// ---- fused KGAT layer: per-head score+softmax+agg + Linear + leaky-ReLU -----
// wave per head (grid-stride). hbase = slice l, outbase = slice l+1.
__global__ __launch_bounds__(256) void k_layer(
        const int* __restrict__ offs, const int* __restrict__ packed,
        const float* __restrict__ hbase, const float* __restrict__ relemb,
        const float* __restrict__ W, float* __restrict__ outbase, int n_heads) {
    __shared__ float Wt[DD * DD];
    __shared__ float xs[4][DD];
    // stage W transposed: Wt[k][j] = W[j][k]; coalesced global reads
    for (int idx = threadIdx.x; idx < DD * DD; idx += 256)
        Wt[(idx & 63) * DD + (idx >> 6)] = W[idx];
    __syncthreads();

    int w = threadIdx.x >> 6, lane = threadIdx.x & 63;
    for (int hd = blockIdx.x * 4 + w; hd < n_heads; hd += gridDim.x * 4) {
        float eh = hbase[(long)hd * ROW + lane];
        float acc = 0.f, ssum = 0.f;
        int p = offs[hd], pe = offs[hd + 1];
        for (; p < pe; ++p) {
            int v = packed[p];
            int tl = v & 0xFFFFF;
            int rl = v >> 20;
            float tt = hbase[(long)tl * ROW + lane];
            float rr = relemb[rl * DD + lane];
            float sc = tt * tanhf(eh + rr);
            #pragma unroll
            for (int off = 32; off; off >>= 1) sc += __shfl_xor(sc, off);
            float se = __expf(sc);
            acc += se * tt;
            ssum += se;
        }
        float x = eh + acc / (ssum + 1e-10f);
        xs[w][lane] = x;                 // wave-private slot: no barrier needed
        float y = 0.f;
        #pragma unroll
        for (int k = 0; k < DD; ++k)
            y += xs[w][k] * Wt[k * DD + lane];
        y = y >= 0.f ? y : 0.2f * y;
        outbase[(long)hd * ROW + lane] = y;
    }
}

extern "C" void kernel_launch(void* const* d_in, const int* in_sizes, int n_in,
                              void* d_out, int out_size, void* d_ws, size_t ws_size,
                              hipStream_t stream) {
    const int*   heads = (const int*)d_in[0];
    const int*   rels  = (const int*)d_in[1];
    const int*   tails = (const int*)d_in[2];
    const float* ent   = (const float*)d_in[3];
    const float* rel   = (const float*)d_in[4];
    const float* Ws    = (const float*)d_in[5];
    float* out = (float*)d_out;

    const int nE = in_sizes[0];
    const int N  = in_sizes[3] / DD;
    const int L  = in_sizes[5] / (DD * DD);
    const int NREL = in_sizes[4] / (L * DD);

    int* offs    = (int*)d_ws;           // [N+1]
    int* running = offs + (N + 1);       // [N] (counts, then running cursor)
    int* packed  = running + N;          // [E]
    // partials lives in the TAIL of packed: read by scan kernels strictly
    // BEFORE k_scatter writes packed (stream order). 128 slots >= nchunks.
    int* partials = packed + nE - 128;

    dim3 blk(256);
    int copy_blocks = (N * 16 + 255) / 256;
    int nchunks = (N + CHUNK - 1) / CHUNK;   // 98 for N=100000

    k_copy_embed<<<copy_blocks, blk, 0, stream>>>(ent, out, N);

    // ---- CSR build (same work every call; no static state) ----
    hipMemsetAsync(running, 0, (size_t)N * sizeof(int), stream);
    k_count<<<(nE + 255) / 256, blk, 0, stream>>>(heads, running, nE);
    k_scan_chunk<<<nchunks, blk, 0, stream>>>(running, offs, partials, N);
    k_scan_part<<<1, 128, 0, stream>>>(partials, nchunks);
    k_scan_add<<<(N + 1 + 255) / 256, blk, 0, stream>>>(offs, partials, N, nE);
    hipMemcpyAsync(running, offs, (size_t)N * sizeof(int),
                   hipMemcpyDeviceToDevice, stream);
    k_scatter<<<(nE + 255) / 256, blk, 0, stream>>>(heads, rels, tails, running, packed, nE);

    // ---- layers ----
    for (int l = 0; l < L; ++l) {
        k_layer<<<2048, blk, 0, stream>>>(
            offs, packed, out + l * DD, rel + (long)l * NREL * DD,
            Ws + (long)l * DD * DD, out + (l + 1) * DD, N);
    }
}

// Round 4
// 553.534 us; speedup vs baseline: 3.4522x; 1.7426x over previous
//
#include <hip/hip_runtime.h>

#define DD 64
#define ROW 256        // output row stride in floats: D*(L+1)
#define CHUNK 1024     // scan chunk

// ---- copy entity_embed -> d_out slice 0 -------------------------------------
__global__ void k_copy_embed(const float* __restrict__ ent, float* __restrict__ out, int n_rows) {
    int idx = blockIdx.x * blockDim.x + threadIdx.x;   // over n_rows*16 float4s
    int total = n_rows * 16;
    if (idx >= total) return;
    int n = idx >> 4, q = idx & 15;
    const float4* src = (const float4*)(ent + (long)n * DD);
    float4* dst = (float4*)(out + (long)n * ROW);
    dst[q] = src[q];
}

// ---- CSR build: count edges per head ---------------------------------------
__global__ void k_count(const int* __restrict__ heads, int* __restrict__ counts, int nE) {
    int e = blockIdx.x * 256 + threadIdx.x;
    if (e >= nE) return;
    atomicAdd(counts + heads[e], 1);
}

// ---- scan step 1: per-chunk exclusive scan + chunk totals -------------------
__global__ __launch_bounds__(256) void k_scan_chunk(
        const int* __restrict__ counts, int* __restrict__ offs,
        int* __restrict__ partials, int n) {
    __shared__ int lds[256];
    int base = blockIdx.x * CHUNK;
    int t = threadIdx.x;
    int c[4]; int sum = 0;
    #pragma unroll
    for (int j = 0; j < 4; ++j) {
        int i = base + t * 4 + j;
        c[j] = (i < n) ? counts[i] : 0;
        sum += c[j];
    }
    lds[t] = sum; __syncthreads();
    for (int d = 1; d < 256; d <<= 1) {
        int v = (t >= d) ? lds[t - d] : 0;
        __syncthreads();
        lds[t] += v;
        __syncthreads();
    }
    int excl = lds[t] - sum;
    if (t == 255) partials[blockIdx.x] = lds[255];
    int run = excl;
    #pragma unroll
    for (int j = 0; j < 4; ++j) {
        int i = base + t * 4 + j;
        if (i < n) offs[i] = run;
        run += c[j];
    }
}

// ---- scan step 2: exclusive scan of chunk totals (nb <= 128) ----------------
__global__ __launch_bounds__(128) void k_scan_part(int* __restrict__ partials, int nb) {
    __shared__ int lds[128];
    int t = threadIdx.x;
    int v = (t < nb) ? partials[t] : 0;
    lds[t] = v; __syncthreads();
    for (int d = 1; d < 128; d <<= 1) {
        int u = (t >= d) ? lds[t - d] : 0;
        __syncthreads();
        lds[t] += u;
        __syncthreads();
    }
    if (t < nb) partials[t] = lds[t] - v;
}

// ---- scan step 3: add chunk offsets, finalize offs[n] = nE ------------------
__global__ void k_scan_add(int* __restrict__ offs, const int* __restrict__ partials,
                           int n, int nE) {
    int i = blockIdx.x * 256 + threadIdx.x;
    if (i < n)       offs[i] += partials[i >> 10];
    else if (i == n) offs[n] = nE;
}

// ---- scatter edges into CSR order; pack tail | (rel<<20) --------------------
__global__ void k_scatter(const int* __restrict__ heads, const int* __restrict__ rels,
                          const int* __restrict__ tails, int* __restrict__ running,
                          int* __restrict__ packed, int nE) {
    int e = blockIdx.x * 256 + threadIdx.x;
    if (e >= nE) return;
    int h = heads[e];
    int pos = atomicAdd(running + h, 1);
    packed[pos] = tails[e] | (rels[e] << 20);
}

// ---- fused KGAT layer -------------------------------------------------------
// wave per head; 4 edge-groups x 16 lanes, float4 per lane (4 dims).
// Edge descriptors batch-loaded (64/chunk) then distributed via shuffle.
// 1-deep software pipeline on the e_t / e_r gathers.
__global__ __launch_bounds__(256) void k_layer(
        const int* __restrict__ offs, const int* __restrict__ packed,
        const float* __restrict__ hbase, const float* __restrict__ relemb,
        const float* __restrict__ W, float* __restrict__ outbase,
        int n_heads, int nE) {
    __shared__ float Wt[DD * 65];      // padded transpose: Wt[k*65+j] = W[j][k]
    __shared__ float xs[4][DD];
    for (int idx = threadIdx.x; idx < DD * DD; idx += 256)
        Wt[(idx & 63) * 65 + (idx >> 6)] = W[idx];   // 2-way bank alias: free
    __syncthreads();

    int w = threadIdx.x >> 6, lane = threadIdx.x & 63;
    int g = lane >> 4, s = lane & 15;      // group 0..3, sublane 0..15

    for (int hd = blockIdx.x * 4 + w; hd < n_heads; hd += gridDim.x * 4) {
        const float4 eh4 = *(const float4*)(hbase + (long)hd * ROW + 4 * s);
        float4 acc = make_float4(0.f, 0.f, 0.f, 0.f);
        float ssum = 0.f;
        int p0 = offs[hd], pe = offs[hd + 1];

        for (int cbase = p0; cbase < pe; cbase += 64) {
            int clen = min(pe - cbase, 64);
            int vAll = packed[min(cbase + lane, nE - 1)];

            // prologue: descriptor + gathers for group-edge g
            int ix0 = (g < clen) ? g : 0;
            int v0 = __shfl(vAll, ix0);
            float4 tt = *(const float4*)(hbase + (long)(v0 & 0xFFFFF) * ROW + 4 * s);
            float4 rr = *(const float4*)(relemb + (v0 >> 20) * DD + 4 * s);

            for (int i = 0; i < clen; i += 4) {
                // prefetch iteration i+4 (clamped; redundant on last iter, cached)
                int ixn = i + 4 + g;
                ixn = (ixn < clen) ? ixn : 0;
                int vn = __shfl(vAll, ixn);
                float4 ttn = *(const float4*)(hbase + (long)(vn & 0xFFFFF) * ROW + 4 * s);
                float4 rrn = *(const float4*)(relemb + (vn >> 20) * DD + 4 * s);

                // score = e_t . tanh(e_h + e_r), fast tanh = 1 - 2/(e^2x + 1)
                float sc = 0.f;
                #pragma unroll
                for (int q = 0; q < 4; ++q) {
                    float xq = (&eh4.x)[q] + (&rr.x)[q];
                    float t = __expf(2.f * xq);
                    float th = 1.f - 2.f / (t + 1.f);
                    sc += (&tt.x)[q] * th;
                }
                #pragma unroll
                for (int off = 1; off <= 8; off <<= 1) sc += __shfl_xor(sc, off);
                bool valid = (i + g) < clen;
                float se = valid ? __expf(sc) : 0.f;
                ssum += se;
                acc.x += se * tt.x; acc.y += se * tt.y;
                acc.z += se * tt.z; acc.w += se * tt.w;
                tt = ttn; rr = rrn;
            }
        }

        // combine the 4 groups' partial sums (lanes with equal s share dims)
        #pragma unroll
        for (int off = 16; off <= 32; off <<= 1) {
            acc.x += __shfl_xor(acc.x, off);
            acc.y += __shfl_xor(acc.y, off);
            acc.z += __shfl_xor(acc.z, off);
            acc.w += __shfl_xor(acc.w, off);
            ssum  += __shfl_xor(ssum,  off);
        }
        float inv = 1.f / (ssum + 1e-10f);
        float4 x4;
        x4.x = eh4.x + acc.x * inv;  x4.y = eh4.y + acc.y * inv;
        x4.z = eh4.z + acc.z * inv;  x4.w = eh4.w + acc.w * inv;
        if (g == 0) *(float4*)(&xs[w][4 * s]) = x4;   // wave-private slot

        // epilogue: y = leaky_relu(x @ W^T), one output dim per lane
        float y = 0.f;
        const float* xw = xs[w];
        #pragma unroll
        for (int k4 = 0; k4 < DD; k4 += 4) {
            float4 xv = *(const float4*)(xw + k4);
            y += xv.x * Wt[(k4 + 0) * 65 + lane];
            y += xv.y * Wt[(k4 + 1) * 65 + lane];
            y += xv.z * Wt[(k4 + 2) * 65 + lane];
            y += xv.w * Wt[(k4 + 3) * 65 + lane];
        }
        y = y >= 0.f ? y : 0.2f * y;
        outbase[(long)hd * ROW + lane] = y;
    }
}

extern "C" void kernel_launch(void* const* d_in, const int* in_sizes, int n_in,
                              void* d_out, int out_size, void* d_ws, size_t ws_size,
                              hipStream_t stream) {
    const int*   heads = (const int*)d_in[0];
    const int*   rels  = (const int*)d_in[1];
    const int*   tails = (const int*)d_in[2];
    const float* ent   = (const float*)d_in[3];
    const float* rel   = (const float*)d_in[4];
    const float* Ws    = (const float*)d_in[5];
    float* out = (float*)d_out;

    const int nE = in_sizes[0];
    const int N  = in_sizes[3] / DD;
    const int L  = in_sizes[5] / (DD * DD);
    const int NREL = in_sizes[4] / (L * DD);

    int* offs    = (int*)d_ws;           // [N+1]
    int* running = offs + (N + 1);       // [N] (counts, then running cursor)
    int* packed  = running + N;          // [E]
    // partials in the TAIL of packed: consumed by scan kernels strictly
    // BEFORE k_scatter writes packed (stream order). 128 slots >= nchunks.
    int* partials = packed + nE - 128;

    dim3 blk(256);
    int copy_blocks = (N * 16 + 255) / 256;
    int nchunks = (N + CHUNK - 1) / CHUNK;   // 98 for N=100000

    k_copy_embed<<<copy_blocks, blk, 0, stream>>>(ent, out, N);

    // ---- CSR build (same work every call; no static state) ----
    hipMemsetAsync(running, 0, (size_t)N * sizeof(int), stream);
    k_count<<<(nE + 255) / 256, blk, 0, stream>>>(heads, running, nE);
    k_scan_chunk<<<nchunks, blk, 0, stream>>>(running, offs, partials, N);
    k_scan_part<<<1, 128, 0, stream>>>(partials, nchunks);
    k_scan_add<<<(N + 1 + 255) / 256, blk, 0, stream>>>(offs, partials, N, nE);
    hipMemcpyAsync(running, offs, (size_t)N * sizeof(int),
                   hipMemcpyDeviceToDevice, stream);
    k_scatter<<<(nE + 255) / 256, blk, 0, stream>>>(heads, rels, tails, running, packed, nE);

    // ---- layers ----
    for (int l = 0; l < L; ++l) {
        k_layer<<<2048, blk, 0, stream>>>(
            offs, packed, out + l * DD, rel + (long)l * NREL * DD,
            Ws + (long)l * DD * DD, out + (l + 1) * DD, N, nE);
    }
}

// Round 5
// 500.490 us; speedup vs baseline: 3.8181x; 1.1060x over previous
//
#include <hip/hip_runtime.h>

#define DD 64
#define ROW 256        // output row stride in floats: D*(L+1)
#define CHUNK 1024     // scan chunk

// ---- copy entity_embed -> d_out slice 0 -------------------------------------
__global__ void k_copy_embed(const float* __restrict__ ent, float* __restrict__ out, int n_rows) {
    int idx = blockIdx.x * blockDim.x + threadIdx.x;   // over n_rows*16 float4s
    int total = n_rows * 16;
    if (idx >= total) return;
    int n = idx >> 4, q = idx & 15;
    const float4* src = (const float4*)(ent + (long)n * DD);
    float4* dst = (float4*)(out + (long)n * ROW);
    dst[q] = src[q];
}

// ---- CSR build: count edges per head ---------------------------------------
__global__ void k_count(const int* __restrict__ heads, int* __restrict__ counts, int nE) {
    int e = blockIdx.x * 256 + threadIdx.x;
    if (e >= nE) return;
    atomicAdd(counts + heads[e], 1);
}

// ---- scan step 1: per-chunk exclusive scan + chunk totals -------------------
__global__ __launch_bounds__(256) void k_scan_chunk(
        const int* __restrict__ counts, int* __restrict__ offs,
        int* __restrict__ partials, int n) {
    __shared__ int lds[256];
    int base = blockIdx.x * CHUNK;
    int t = threadIdx.x;
    int c[4]; int sum = 0;
    #pragma unroll
    for (int j = 0; j < 4; ++j) {
        int i = base + t * 4 + j;
        c[j] = (i < n) ? counts[i] : 0;
        sum += c[j];
    }
    lds[t] = sum; __syncthreads();
    for (int d = 1; d < 256; d <<= 1) {
        int v = (t >= d) ? lds[t - d] : 0;
        __syncthreads();
        lds[t] += v;
        __syncthreads();
    }
    int excl = lds[t] - sum;
    if (t == 255) partials[blockIdx.x] = lds[255];
    int run = excl;
    #pragma unroll
    for (int j = 0; j < 4; ++j) {
        int i = base + t * 4 + j;
        if (i < n) offs[i] = run;
        run += c[j];
    }
}

// ---- scan step 2: exclusive scan of chunk totals (nb <= 128) ----------------
__global__ __launch_bounds__(128) void k_scan_part(int* __restrict__ partials, int nb) {
    __shared__ int lds[128];
    int t = threadIdx.x;
    int v = (t < nb) ? partials[t] : 0;
    lds[t] = v; __syncthreads();
    for (int d = 1; d < 128; d <<= 1) {
        int u = (t >= d) ? lds[t - d] : 0;
        __syncthreads();
        lds[t] += u;
        __syncthreads();
    }
    if (t < nb) partials[t] = lds[t] - v;
}

// ---- scan step 3: add chunk offsets, write scatter cursors, finalize --------
__global__ void k_scan_add(int* __restrict__ offs, int* __restrict__ running,
                           const int* __restrict__ partials, int n, int nE) {
    int i = blockIdx.x * 256 + threadIdx.x;
    if (i < n) {
        int v = offs[i] + partials[i >> 10];
        offs[i] = v;
        running[i] = v;     // scatter cursor init (replaces d2d memcpy)
    } else if (i == n) {
        offs[n] = nE;
    }
}

// ---- scatter edges into CSR order; pack tail | (rel<<20) --------------------
__global__ void k_scatter(const int* __restrict__ heads, const int* __restrict__ rels,
                          const int* __restrict__ tails, int* __restrict__ running,
                          int* __restrict__ packed, int nE) {
    int e = blockIdx.x * 256 + threadIdx.x;
    if (e >= nE) return;
    int h = heads[e];
    int pos = atomicAdd(running + h, 1);
    packed[pos] = tails[e] | (rels[e] << 20);
}

// ---- fused KGAT layer -------------------------------------------------------
// wave per head; 4 edge-groups x 16 lanes, float4 per lane (4 dims).
// Edge descriptors batch-loaded (64/chunk) then distributed via shuffle.
// 2-deep software pipeline, 8 edges per iteration (4 gathers in flight).
__global__ __launch_bounds__(256) void k_layer(
        const int* __restrict__ offs, const int* __restrict__ packed,
        const float* __restrict__ hbase, const float* __restrict__ relemb,
        const float* __restrict__ W, float* __restrict__ outbase,
        int n_heads, int nE) {
    __shared__ float Wt[DD * 65];      // padded transpose: Wt[k*65+j] = W[j][k]
    __shared__ float xs[4][DD];
    for (int idx = threadIdx.x; idx < DD * DD; idx += 256)
        Wt[(idx & 63) * 65 + (idx >> 6)] = W[idx];   // 2-way bank alias: free
    __syncthreads();

    int w = threadIdx.x >> 6, lane = threadIdx.x & 63;
    int g = lane >> 4, s = lane & 15;      // group 0..3, sublane 0..15

    for (int hd = blockIdx.x * 4 + w; hd < n_heads; hd += gridDim.x * 4) {
        const float4 eh4 = *(const float4*)(hbase + (long)hd * ROW + 4 * s);
        float4 acc = make_float4(0.f, 0.f, 0.f, 0.f);
        float ssum = 0.f;
        int p0 = offs[hd], pe = offs[hd + 1];

        for (int cbase = p0; cbase < pe; cbase += 64) {
            int clen = min(pe - cbase, 64);
            int vAll = packed[min(cbase + lane, nE - 1)];

            // prologue: stages 0 (edges g) and 1 (edges 4+g)
            int i0 = (g < clen) ? g : 0;
            int i1 = (4 + g < clen) ? 4 + g : 0;
            int v0 = __shfl(vAll, i0);
            int v1 = __shfl(vAll, i1);
            float4 tt0 = *(const float4*)(hbase + (long)(v0 & 0xFFFFF) * ROW + 4 * s);
            float4 rr0 = *(const float4*)(relemb + (v0 >> 20) * DD + 4 * s);
            float4 tt1 = *(const float4*)(hbase + (long)(v1 & 0xFFFFF) * ROW + 4 * s);
            float4 rr1 = *(const float4*)(relemb + (v1 >> 20) * DD + 4 * s);

            for (int i = 0; i < clen; i += 8) {
                // prefetch stages for i+8 (clamped; redundant tail hits cache)
                int ia = i + 8 + g;  ia = (ia < clen) ? ia : 0;
                int ib = i + 12 + g; ib = (ib < clen) ? ib : 0;
                int va = __shfl(vAll, ia);
                int vb = __shfl(vAll, ib);
                float4 tta = *(const float4*)(hbase + (long)(va & 0xFFFFF) * ROW + 4 * s);
                float4 rra = *(const float4*)(relemb + (va >> 20) * DD + 4 * s);
                float4 ttb = *(const float4*)(hbase + (long)(vb & 0xFFFFF) * ROW + 4 * s);
                float4 rrb = *(const float4*)(relemb + (vb >> 20) * DD + 4 * s);

                // ---- stage 0: edges i+g ----
                {
                    float sc = 0.f;
                    #pragma unroll
                    for (int q = 0; q < 4; ++q) {
                        float xq = (&eh4.x)[q] + (&rr0.x)[q];
                        float t = __expf(2.f * xq);
                        float th = 1.f - 2.f * __builtin_amdgcn_rcpf(t + 1.f);
                        sc += (&tt0.x)[q] * th;
                    }
                    #pragma unroll
                    for (int off = 1; off <= 8; off <<= 1) sc += __shfl_xor(sc, off);
                    float se = ((i + g) < clen) ? __expf(sc) : 0.f;
                    ssum += se;
                    acc.x += se * tt0.x; acc.y += se * tt0.y;
                    acc.z += se * tt0.z; acc.w += se * tt0.w;
                }
                // ---- stage 1: edges i+4+g ----
                {
                    float sc = 0.f;
                    #pragma unroll
                    for (int q = 0; q < 4; ++q) {
                        float xq = (&eh4.x)[q] + (&rr1.x)[q];
                        float t = __expf(2.f * xq);
                        float th = 1.f - 2.f * __builtin_amdgcn_rcpf(t + 1.f);
                        sc += (&tt1.x)[q] * th;
                    }
                    #pragma unroll
                    for (int off = 1; off <= 8; off <<= 1) sc += __shfl_xor(sc, off);
                    float se = ((i + 4 + g) < clen) ? __expf(sc) : 0.f;
                    ssum += se;
                    acc.x += se * tt1.x; acc.y += se * tt1.y;
                    acc.z += se * tt1.z; acc.w += se * tt1.w;
                }
                tt0 = tta; rr0 = rra; tt1 = ttb; rr1 = rrb;
            }
        }

        // combine the 4 groups' partial sums (lanes with equal s share dims)
        #pragma unroll
        for (int off = 16; off <= 32; off <<= 1) {
            acc.x += __shfl_xor(acc.x, off);
            acc.y += __shfl_xor(acc.y, off);
            acc.z += __shfl_xor(acc.z, off);
            acc.w += __shfl_xor(acc.w, off);
            ssum  += __shfl_xor(ssum,  off);
        }
        float inv = 1.f / (ssum + 1e-10f);
        float4 x4;
        x4.x = eh4.x + acc.x * inv;  x4.y = eh4.y + acc.y * inv;
        x4.z = eh4.z + acc.z * inv;  x4.w = eh4.w + acc.w * inv;
        if (g == 0) *(float4*)(&xs[w][4 * s]) = x4;   // wave-private slot

        // epilogue: y = leaky_relu(x @ W^T), one output dim per lane
        float y = 0.f;
        const float* xw = xs[w];
        #pragma unroll
        for (int k4 = 0; k4 < DD; k4 += 4) {
            float4 xv = *(const float4*)(xw + k4);
            y += xv.x * Wt[(k4 + 0) * 65 + lane];
            y += xv.y * Wt[(k4 + 1) * 65 + lane];
            y += xv.z * Wt[(k4 + 2) * 65 + lane];
            y += xv.w * Wt[(k4 + 3) * 65 + lane];
        }
        y = y >= 0.f ? y : 0.2f * y;
        outbase[(long)hd * ROW + lane] = y;
    }
}

extern "C" void kernel_launch(void* const* d_in, const int* in_sizes, int n_in,
                              void* d_out, int out_size, void* d_ws, size_t ws_size,
                              hipStream_t stream) {
    const int*   heads = (const int*)d_in[0];
    const int*   rels  = (const int*)d_in[1];
    const int*   tails = (const int*)d_in[2];
    const float* ent   = (const float*)d_in[3];
    const float* rel   = (const float*)d_in[4];
    const float* Ws    = (const float*)d_in[5];
    float* out = (float*)d_out;

    const int nE = in_sizes[0];
    const int N  = in_sizes[3] / DD;
    const int L  = in_sizes[5] / (DD * DD);
    const int NREL = in_sizes[4] / (L * DD);

    int* offs    = (int*)d_ws;           // [N+1]
    int* running = offs + (N + 1);       // [N] (counts, then scatter cursor)
    int* packed  = running + N;          // [E]
    // partials in the TAIL of packed: consumed by scan kernels strictly
    // BEFORE k_scatter writes packed (stream order). 128 slots >= nchunks.
    int* partials = packed + nE - 128;

    dim3 blk(256);
    int copy_blocks = (N * 16 + 255) / 256;
    int nchunks = (N + CHUNK - 1) / CHUNK;   // 98 for N=100000

    k_copy_embed<<<copy_blocks, blk, 0, stream>>>(ent, out, N);

    // ---- CSR build (same work every call; no static state) ----
    hipMemsetAsync(running, 0, (size_t)N * sizeof(int), stream);
    k_count<<<(nE + 255) / 256, blk, 0, stream>>>(heads, running, nE);
    k_scan_chunk<<<nchunks, blk, 0, stream>>>(running, offs, partials, N);
    k_scan_part<<<1, 128, 0, stream>>>(partials, nchunks);
    k_scan_add<<<(N + 1 + 255) / 256, blk, 0, stream>>>(offs, running, partials, N, nE);
    k_scatter<<<(nE + 255) / 256, blk, 0, stream>>>(heads, rels, tails, running, packed, nE);

    // ---- layers ----
    for (int l = 0; l < L; ++l) {
        k_layer<<<2048, blk, 0, stream>>>(
            offs, packed, out + l * DD, rel + (long)l * NREL * DD,
            Ws + (long)l * DD * DD, out + (l + 1) * DD, N, nE);
    }
}